// Round 9
// baseline (2915.022 us; speedup 1.0000x reference)
//
#include <hip/hip_runtime.h>
#include <cmath>

// ---- problem dims (fixed per reference) ----
#define YCH 8        // y_channels
#define NTR 16       // trials
#define LLEN 4096    // trial length
#define CK  16       // kernels per channel
#define KS  64       // kernel size
#define ENC 4033     // LLEN - KS + 1
#define NP  128      // YCH*NTR independent problems
#define INV_LIP 0.1f     // 1/10
#define THRESH 0.01f     // LAM/LIP = 0.1/10

#define XW4 272          // float4s per 1088-float window tile

// keep a loaded float4 in VGPRs: value becomes opaque -> compiler cannot
// rematerialize it from LDS (the demotion that caused 1.4e7 bank conflicts)
#define PIN4(v) asm volatile("" : "+v"((v).x), "+v"((v).y), "+v"((v).z), "+v"((v).w))

// B over [gi4, gi4+3], zero outside [0, ENC):  B = a + gamma*(a - p)
__device__ __forceinline__ float4 loadB4(const float* __restrict__ A,
                                         const float* __restrict__ P,
                                         float gamma, size_t coff, int gi4)
{
    if (gi4 >= 0 && gi4 + 3 < ENC) {
        float4 a = *(const float4*)(A + coff + gi4);
        float4 p = *(const float4*)(P + coff + gi4);
        return make_float4(fmaf(gamma, a.x - p.x, a.x),
                           fmaf(gamma, a.y - p.y, a.y),
                           fmaf(gamma, a.z - p.z, a.z),
                           fmaf(gamma, a.w - p.w, a.w));
    }
    float r[4];
    #pragma unroll
    for (int j = 0; j < 4; ++j) {
        int gi = gi4 + j;
        if (gi >= 0 && gi < ENC) {
            float a = A[coff + gi], p = P[coff + gi];
            r[j] = fmaf(gamma, a - p, a);
        } else r[j] = 0.f;
    }
    return make_float4(r[0], r[1], r[2], r[3]);
}

// =====================================================================
// resid_quad: part[q][p][t] = sum_{c in quad q, k} B[p,c,t-k]*H[ch,c,k]
// block = (ttile=1024, q, p) -> grid (4,4,128) x 128 thr (2 waves),
// 8 outputs/thread. Stage quad's 4 B-windows in LDS, ONE barrier, then a
// rolling named A,B,C float4 window, PINNED into VGPRs via inline asm so
// the compiler cannot demote operands back to strided LDS re-reads.
//   out t=t0+8*tid+j: acc[j] += xs[8*tid + 64 + j - k]*h[k]
//   k = 63-4g-m  ->  acc[j] += w[4g+m+j+1 - 4g]*hc[15-g][3-m], w={A,B,C}
// =====================================================================
__global__ __launch_bounds__(128, 4) void resid_quad(
    const float* __restrict__ H,
    const float* __restrict__ Acur, const float* __restrict__ Aprev,
    float gamma, float* __restrict__ part)
{
    __shared__ __align__(16) float xs[4 * 1088];  // 17408 B
    __shared__ __align__(16) float hs[4 * KS];    //  1024 B
    const int tid = threadIdx.x;
    const int t0  = blockIdx.x * 1024;
    const int c0  = blockIdx.y * 4;
    const int p   = blockIdx.z;
    const int ch  = p >> 4;

    if (tid < 64)
        ((float4*)hs)[tid] = ((const float4*)(H + ((size_t)ch * CK + c0) * KS))[tid];

    const size_t pbase = (size_t)p * CK * ENC;
    // stage 4 channels x 272 f4 = 1088 f4 (8.5 per thread)
    #pragma unroll
    for (int s = 0; s < 9; ++s) {
        int l4 = tid + 128 * s;
        if (l4 < 4 * XW4) {
            int c   = l4 / XW4;
            int off = l4 - c * XW4;
            ((float4*)xs)[l4] = loadB4(Acur, Aprev, gamma,
                                       pbase + (size_t)(c0 + c) * ENC,
                                       t0 - 64 + 4 * off);
        }
    }
    __syncthreads();

    float acc[8] = {0.f,0.f,0.f,0.f,0.f,0.f,0.f,0.f};

    #pragma unroll
    for (int cc = 0; cc < 4; ++cc) {
        const float4* xr = (const float4*)(xs + cc * 1088) + 2 * tid;
        const float4* hc = (const float4*)(hs + cc * KS);
        float4 A = xr[0]; PIN4(A);
        float4 B = xr[1]; PIN4(B);
        float4 C = xr[2]; PIN4(C);
        #pragma unroll
        for (int g = 0; g < 16; ++g) {
            float4 h4 = hc[15 - g];
            float hh[4] = {h4.w, h4.z, h4.y, h4.x};   // hh[m] = h[63-4g-m]
            float w[12] = {A.x, A.y, A.z, A.w, B.x, B.y, B.z, B.w,
                           C.x, C.y, C.z, C.w};
            #pragma unroll
            for (int m = 0; m < 4; ++m)
                #pragma unroll
                for (int j = 0; j < 8; ++j)
                    acc[j] = fmaf(w[m + j + 1], hh[m], acc[j]);
            A = B; B = C;
            if (g < 15) { C = xr[g + 3]; PIN4(C); }
        }
    }

    const int t = t0 + 8 * tid;
    float* dst = part + ((size_t)blockIdx.y * NP + p) * LLEN + t;
    *(float4*)(dst)     = make_float4(acc[0], acc[1], acc[2], acc[3]);
    *(float4*)(dst + 4) = make_float4(acc[4], acc[5], acc[6], acc[7]);
}

// =====================================================================
// fista_quad (unchanged, ~17us): block = (itile, cquad, p).
//   staging: rs = y - sum_q part[q]  (reduce fused; first: rs = y)
//   g[c,i] = sum_k rs[i+k]*H[ch,c,k];  x_new = relu(B + g/LIP - thr)
// =====================================================================
__global__ __launch_bounds__(256) void fista_quad(
    const float* __restrict__ y, const float* __restrict__ part,
    const float* __restrict__ H,
    const float* __restrict__ Acur, const float* __restrict__ Aprev,
    float gamma, int first, float* __restrict__ Anext)
{
    __shared__ __align__(16) float rs[XW4 * 4];
    __shared__ __align__(16) float hs[4 * KS];
    const int tid = threadIdx.x;
    const int i0  = blockIdx.x * 1024;
    const int c0  = blockIdx.y * 4;
    const int p   = blockIdx.z;
    const int n = p & 15, ch = p >> 4;

    if (tid < 64)
        ((float4*)hs)[tid] = ((const float4*)(H + ((size_t)ch * CK + c0) * KS))[tid];

    const float* ybase = y + ((size_t)n * YCH + ch) * LLEN;
    #pragma unroll
    for (int s = 0; s < 2; ++s) {
        int l4 = tid + 256 * s;
        if (l4 < XW4) {
            int gi4 = i0 + 4 * l4;
            float4 v;
            if (gi4 + 3 < LLEN) {
                v = *(const float4*)(ybase + gi4);
                if (!first) {
                    #pragma unroll
                    for (int q = 0; q < 4; ++q) {
                        float4 pv = *(const float4*)(part + ((size_t)q * NP + p) * LLEN + gi4);
                        v.x -= pv.x; v.y -= pv.y; v.z -= pv.z; v.w -= pv.w;
                    }
                }
            } else {
                float r[4];
                #pragma unroll
                for (int j = 0; j < 4; ++j) {
                    int gi = gi4 + j;
                    if (gi < LLEN) {
                        float t = ybase[gi];
                        if (!first) {
                            #pragma unroll
                            for (int q = 0; q < 4; ++q)
                                t -= part[((size_t)q * NP + p) * LLEN + gi];
                        }
                        r[j] = t;
                    } else r[j] = 0.f;
                }
                v = make_float4(r[0], r[1], r[2], r[3]);
            }
            ((float4*)rs)[l4] = v;
        }
    }
    __syncthreads();

    // hoisted register window rs[4*tid .. 4*tid+67], shared by 4 channels
    float wf[68];
    const float4* rr = (const float4*)rs + tid;
    #pragma unroll
    for (int q = 0; q < 17; ++q) {
        float4 t4 = rr[q];
        wf[4*q] = t4.x; wf[4*q+1] = t4.y; wf[4*q+2] = t4.z; wf[4*q+3] = t4.w;
    }

    const int i = i0 + 4 * tid;
    const size_t pb = (size_t)p * CK * ENC;
    const bool vec = (i + 3 < ENC);

    float4 a0 = make_float4(0,0,0,0), p0 = make_float4(0,0,0,0);
    if (!first && vec) {
        a0 = *(const float4*)(Acur  + pb + (size_t)c0 * ENC + i);
        p0 = *(const float4*)(Aprev + pb + (size_t)c0 * ENC + i);
    }

    for (int cc = 0; cc < 4; ++cc) {
        float4 a1 = make_float4(0,0,0,0), p1 = make_float4(0,0,0,0);
        if (!first && vec && cc < 3) {
            a1 = *(const float4*)(Acur  + pb + (size_t)(c0 + cc + 1) * ENC + i);
            p1 = *(const float4*)(Aprev + pb + (size_t)(c0 + cc + 1) * ENC + i);
        }

        float acc[4] = {0.f, 0.f, 0.f, 0.f};
        const float4* hc = (const float4*)(hs + cc * KS);
        #pragma unroll
        for (int g = 0; g < 16; ++g) {
            float4 h4 = hc[g];
            float hh[4] = {h4.x, h4.y, h4.z, h4.w};
            #pragma unroll
            for (int m = 0; m < 4; ++m) {
                const int k = 4 * g + m;
                #pragma unroll
                for (int j = 0; j < 4; ++j)
                    acc[j] = fmaf(wf[k + j], hh[m], acc[j]);
            }
        }

        const size_t idx = pb + (size_t)(c0 + cc) * ENC + i;
        if (vec) {
            float B[4] = {0.f, 0.f, 0.f, 0.f};
            if (!first) {
                float av[4] = {a0.x, a0.y, a0.z, a0.w};
                float pv[4] = {p0.x, p0.y, p0.z, p0.w};
                #pragma unroll
                for (int j = 0; j < 4; ++j) B[j] = fmaf(gamma, av[j] - pv[j], av[j]);
            }
            float4 o;
            o.x = fmaxf(fmaf(acc[0], INV_LIP, B[0]) - THRESH, 0.f);
            o.y = fmaxf(fmaf(acc[1], INV_LIP, B[1]) - THRESH, 0.f);
            o.z = fmaxf(fmaf(acc[2], INV_LIP, B[2]) - THRESH, 0.f);
            o.w = fmaxf(fmaf(acc[3], INV_LIP, B[3]) - THRESH, 0.f);
            *(float4*)(Anext + idx) = o;
        } else if (i < ENC) {
            #pragma unroll
            for (int j = 0; j < 4; ++j) {
                if (i + j < ENC) {
                    float B = 0.f;
                    if (!first) {
                        float a = Acur[idx + j], pp = Aprev[idx + j];
                        B = fmaf(gamma, a - pp, a);
                    }
                    Anext[idx + j] = fmaxf(fmaf(acc[j], INV_LIP, B) - THRESH, 0.f);
                }
            }
        }
        a0 = a1; p0 = p1;
    }
}

// =====================================================================
extern "C" void kernel_launch(void* const* d_in, const int* in_sizes, int n_in,
                              void* d_out, int out_size, void* d_ws, size_t ws_size,
                              hipStream_t stream)
{
    const float* y = (const float*)d_in[0];   // [NTR, YCH, LLEN]
    const float* H = (const float*)d_in[1];   // [YCH, CK, 1, KS]
    const size_t XSZ = (size_t)NP * CK * ENC; // 8,259,584 floats

    float* bufA = (float*)d_ws;               // A_t for even t
    float* bufB = (float*)d_out;              // A_t for odd t (A9 -> d_out)
    float* part = bufA + XSZ;                 // [4][NP][LLEN] partial synth sums

    double s[11]; s[0] = 1.0;
    for (int t = 1; t <= 10; ++t) s[t] = 0.5 * (1.0 + sqrt(1.0 + 4.0 * s[t-1] * s[t-1]));

    dim3 gR(4, 4, NP), gF(4, 4, NP);

    for (int t = 0; t < 10; ++t) {
        float gamma = (t == 0) ? 0.f : (float)((s[t-1] - 1.0) / s[t]);
        float* Anext       = (t & 1) ? bufB : bufA;
        const float* Acur  = (t & 1) ? bufA : bufB;              // A_{t-1}
        const float* Aprev = (t <= 1) ? Acur                     // gamma==0, unused
                                      : ((t & 1) ? bufB : bufA); // A_{t-2}
        if (t == 0) {
            // B_0 = 0 => res = y; fuse into update kernel (first=1)
            fista_quad<<<gF, 256, 0, stream>>>(y, part, H, bufA, bufA, 0.f, 1, bufA);
        } else {
            resid_quad<<<gR, 128, 0, stream>>>(H, Acur, Aprev, gamma, part);
            fista_quad<<<gF, 256, 0, stream>>>(y, part, H, Acur, Aprev, gamma, 0, Anext);
        }
    }
}

// Round 11
// 650.509 us; speedup vs baseline: 4.4811x; 4.4811x over previous
//
#include <hip/hip_runtime.h>
#include <cmath>

// ---- problem dims (fixed per reference) ----
#define YCH 8        // y_channels
#define NTR 16       // trials
#define LLEN 4096    // trial length
#define CK  16       // kernels per channel
#define KS  64       // kernel size
#define ENC 4033     // LLEN - KS + 1
#define NP  128      // YCH*NTR independent problems
#define INV_LIP 0.1f     // 1/10
#define THRESH 0.01f     // LAM/LIP = 0.1/10

#define XW4 272          // float4s per 1088-float window tile

// component of a float4 by compile-time-constant index (folds; no alloca)
#define C4(v, c) ((c) == 0 ? (v).x : (c) == 1 ? (v).y : (c) == 2 ? (v).z : (v).w)
// group-window float f in [0,19] over named regs w0..w4 (folds under unroll)
#define GW(f) ((f) < 4  ? C4(w0, (f))      : \
               (f) < 8  ? C4(w1, (f) - 4)  : \
               (f) < 12 ? C4(w2, (f) - 8)  : \
               (f) < 16 ? C4(w3, (f) - 12) : C4(w4, (f) - 16))

// B over [gi4, gi4+3], zero outside [0, ENC):  B = a + gamma*(a - p)
__device__ __forceinline__ float4 loadB4(const float* __restrict__ A,
                                         const float* __restrict__ P,
                                         float gamma, size_t coff, int gi4)
{
    if (gi4 >= 0 && gi4 + 3 < ENC) {
        float4 a = *(const float4*)(A + coff + gi4);
        float4 p = *(const float4*)(P + coff + gi4);
        return make_float4(fmaf(gamma, a.x - p.x, a.x),
                           fmaf(gamma, a.y - p.y, a.y),
                           fmaf(gamma, a.z - p.z, a.z),
                           fmaf(gamma, a.w - p.w, a.w));
    }
    float r[4];
    #pragma unroll
    for (int j = 0; j < 4; ++j) {
        int gi = gi4 + j;
        if (gi >= 0 && gi < ENC) {
            float a = A[coff + gi], p = P[coff + gi];
            r[j] = fmaf(gamma, a - p, a);
        } else r[j] = 0.f;
    }
    return make_float4(r[0], r[1], r[2], r[3]);
}

// =====================================================================
// resid_quad: part[q][p][t] = sum_{c in quad q, k} B[p,c,t-k]*H[ch,c,k]
// block = (ttile=1024, q, p) -> grid (4,4,128) x 256 thr, 4 outputs/thread.
// Stage quad's 4 B-windows in LDS, ONE barrier. K split into 4 k-groups of
// 16 taps: group kg touches only 5 float4 slots [12-4kg .. 16-4kg] of the
// 68-float window -> rolling named w0..w4 (20 floats live, 16x reuse each).
// Small live set fits the 64-VGPR/8-wave budget => compiler keeps it in
// registers instead of rematerializing strided ds_read_b32 (the 8-way
// bank-conflict disease of r7/r8).
//   identity: out t=t0+4*tid+j needs xs_local[4*tid + 64+j-k], k=16kg+mm;
//   group base float = 4*(12-4kg) => local-in-group f = 16-mm+j in [1,19].
// =====================================================================
__global__ __launch_bounds__(256) void resid_quad(
    const float* __restrict__ H,
    const float* __restrict__ Acur, const float* __restrict__ Aprev,
    float gamma, float* __restrict__ part)
{
    __shared__ __align__(16) float xs[4 * 1088];  // 17408 B
    __shared__ __align__(16) float hs[4 * KS];    //  1024 B
    const int tid = threadIdx.x;
    const int t0  = blockIdx.x * 1024;
    const int c0  = blockIdx.y * 4;
    const int p   = blockIdx.z;
    const int ch  = p >> 4;

    if (tid < 64)
        ((float4*)hs)[tid] = ((const float4*)(H + ((size_t)ch * CK + c0) * KS))[tid];

    const size_t pbase = (size_t)p * CK * ENC;
    // stage 4 channels x 272 f4 = 1088 f4 (4.25 per thread)
    #pragma unroll
    for (int s = 0; s < 5; ++s) {
        int l4 = tid + 256 * s;
        if (l4 < 4 * XW4) {
            int c   = l4 / XW4;
            int off = l4 - c * XW4;
            ((float4*)xs)[l4] = loadB4(Acur, Aprev, gamma,
                                       pbase + (size_t)(c0 + c) * ENC,
                                       t0 - 64 + 4 * off);
        }
    }
    __syncthreads();

    float acc[4] = {0.f, 0.f, 0.f, 0.f};

    #pragma unroll
    for (int cc = 0; cc < 4; ++cc) {
        const float4* xr = (const float4*)(xs + cc * 1088) + tid;
        const float4* hc = (const float4*)(hs + cc * KS);

        float4 w0 = xr[12], w1 = xr[13], w2 = xr[14], w3 = xr[15], w4 = xr[16];
        #pragma unroll
        for (int kg = 0; kg < 4; ++kg) {
            const float4 h0 = hc[4 * kg], h1 = hc[4 * kg + 1];
            const float4 h2 = hc[4 * kg + 2], h3 = hc[4 * kg + 3];
            #pragma unroll
            for (int mm = 0; mm < 16; ++mm) {       // tap k = 16*kg + mm
                const float hm = C4((mm < 4 ? h0 : mm < 8 ? h1 : mm < 12 ? h2 : h3),
                                    mm & 3);
                #pragma unroll
                for (int j = 0; j < 4; ++j)
                    acc[j] = fmaf(GW(16 - mm + j), hm, acc[j]);
            }
            if (kg < 3) {   // roll window down 4 slots; slot 12-4kg reused
                w4 = w0;
                w0 = xr[8 - 4 * kg];
                w1 = xr[9 - 4 * kg];
                w2 = xr[10 - 4 * kg];
                w3 = xr[11 - 4 * kg];
            }
        }
    }

    const int t = t0 + 4 * tid;
    *(float4*)(part + ((size_t)blockIdx.y * NP + p) * LLEN + t) =
        make_float4(acc[0], acc[1], acc[2], acc[3]);
}

// =====================================================================
// fista_quad: EXACT round-7 version (passed, not the bottleneck).
//   staging: rs = y - sum_q part[q]  (reduce fused; first: rs = y)
//   g[c,i] = sum_k rs[i+k]*H[ch,c,k];  x_new = relu(B + g/LIP - thr)
// =====================================================================
__global__ __launch_bounds__(256) void fista_quad(
    const float* __restrict__ y, const float* __restrict__ part,
    const float* __restrict__ H,
    const float* __restrict__ Acur, const float* __restrict__ Aprev,
    float gamma, int first, float* __restrict__ Anext)
{
    __shared__ __align__(16) float rs[XW4 * 4];
    __shared__ __align__(16) float hs[4 * KS];
    const int tid = threadIdx.x;
    const int i0  = blockIdx.x * 1024;
    const int c0  = blockIdx.y * 4;
    const int p   = blockIdx.z;
    const int n = p & 15, ch = p >> 4;

    if (tid < 64)
        ((float4*)hs)[tid] = ((const float4*)(H + ((size_t)ch * CK + c0) * KS))[tid];

    const float* ybase = y + ((size_t)n * YCH + ch) * LLEN;
    #pragma unroll
    for (int s = 0; s < 2; ++s) {
        int l4 = tid + 256 * s;
        if (l4 < XW4) {
            int gi4 = i0 + 4 * l4;
            float4 v;
            if (gi4 + 3 < LLEN) {
                v = *(const float4*)(ybase + gi4);
                if (!first) {
                    #pragma unroll
                    for (int q = 0; q < 4; ++q) {
                        float4 pv = *(const float4*)(part + ((size_t)q * NP + p) * LLEN + gi4);
                        v.x -= pv.x; v.y -= pv.y; v.z -= pv.z; v.w -= pv.w;
                    }
                }
            } else {
                float r[4];
                #pragma unroll
                for (int j = 0; j < 4; ++j) {
                    int gi = gi4 + j;
                    if (gi < LLEN) {
                        float t = ybase[gi];
                        if (!first) {
                            #pragma unroll
                            for (int q = 0; q < 4; ++q)
                                t -= part[((size_t)q * NP + p) * LLEN + gi];
                        }
                        r[j] = t;
                    } else r[j] = 0.f;
                }
                v = make_float4(r[0], r[1], r[2], r[3]);
            }
            ((float4*)rs)[l4] = v;
        }
    }
    __syncthreads();

    // hoisted register window rs[4*tid .. 4*tid+67], shared by 4 channels
    float wf[68];
    const float4* rr = (const float4*)rs + tid;
    #pragma unroll
    for (int q = 0; q < 17; ++q) {
        float4 t4 = rr[q];
        wf[4*q] = t4.x; wf[4*q+1] = t4.y; wf[4*q+2] = t4.z; wf[4*q+3] = t4.w;
    }

    const int i = i0 + 4 * tid;
    const size_t pb = (size_t)p * CK * ENC;
    const bool vec = (i + 3 < ENC);

    float4 a0 = make_float4(0,0,0,0), p0 = make_float4(0,0,0,0);
    if (!first && vec) {
        a0 = *(const float4*)(Acur  + pb + (size_t)c0 * ENC + i);
        p0 = *(const float4*)(Aprev + pb + (size_t)c0 * ENC + i);
    }

    for (int cc = 0; cc < 4; ++cc) {
        float4 a1 = make_float4(0,0,0,0), p1 = make_float4(0,0,0,0);
        if (!first && vec && cc < 3) {
            a1 = *(const float4*)(Acur  + pb + (size_t)(c0 + cc + 1) * ENC + i);
            p1 = *(const float4*)(Aprev + pb + (size_t)(c0 + cc + 1) * ENC + i);
        }

        float acc[4] = {0.f, 0.f, 0.f, 0.f};
        const float4* hc = (const float4*)(hs + cc * KS);
        #pragma unroll
        for (int g = 0; g < 16; ++g) {
            float4 h4 = hc[g];
            float hh[4] = {h4.x, h4.y, h4.z, h4.w};
            #pragma unroll
            for (int m = 0; m < 4; ++m) {
                const int k = 4 * g + m;
                #pragma unroll
                for (int j = 0; j < 4; ++j)
                    acc[j] = fmaf(wf[k + j], hh[m], acc[j]);
            }
        }

        const size_t idx = pb + (size_t)(c0 + cc) * ENC + i;
        if (vec) {
            float B[4] = {0.f, 0.f, 0.f, 0.f};
            if (!first) {
                float av[4] = {a0.x, a0.y, a0.z, a0.w};
                float pv[4] = {p0.x, p0.y, p0.z, p0.w};
                #pragma unroll
                for (int j = 0; j < 4; ++j) B[j] = fmaf(gamma, av[j] - pv[j], av[j]);
            }
            float4 o;
            o.x = fmaxf(fmaf(acc[0], INV_LIP, B[0]) - THRESH, 0.f);
            o.y = fmaxf(fmaf(acc[1], INV_LIP, B[1]) - THRESH, 0.f);
            o.z = fmaxf(fmaf(acc[2], INV_LIP, B[2]) - THRESH, 0.f);
            o.w = fmaxf(fmaf(acc[3], INV_LIP, B[3]) - THRESH, 0.f);
            *(float4*)(Anext + idx) = o;
        } else if (i < ENC) {
            #pragma unroll
            for (int j = 0; j < 4; ++j) {
                if (i + j < ENC) {
                    float B = 0.f;
                    if (!first) {
                        float a = Acur[idx + j], pp = Aprev[idx + j];
                        B = fmaf(gamma, a - pp, a);
                    }
                    Anext[idx + j] = fmaxf(fmaf(acc[j], INV_LIP, B) - THRESH, 0.f);
                }
            }
        }
        a0 = a1; p0 = p1;
    }
}

// =====================================================================
extern "C" void kernel_launch(void* const* d_in, const int* in_sizes, int n_in,
                              void* d_out, int out_size, void* d_ws, size_t ws_size,
                              hipStream_t stream)
{
    const float* y = (const float*)d_in[0];   // [NTR, YCH, LLEN]
    const float* H = (const float*)d_in[1];   // [YCH, CK, 1, KS]
    const size_t XSZ = (size_t)NP * CK * ENC; // 8,259,584 floats

    float* bufA = (float*)d_ws;               // A_t for even t
    float* bufB = (float*)d_out;              // A_t for odd t (A9 -> d_out)
    float* part = bufA + XSZ;                 // [4][NP][LLEN] partial synth sums

    double s[11]; s[0] = 1.0;
    for (int t = 1; t <= 10; ++t) s[t] = 0.5 * (1.0 + sqrt(1.0 + 4.0 * s[t-1] * s[t-1]));

    dim3 gR(4, 4, NP), gF(4, 4, NP);

    for (int t = 0; t < 10; ++t) {
        float gamma = (t == 0) ? 0.f : (float)((s[t-1] - 1.0) / s[t]);
        float* Anext       = (t & 1) ? bufB : bufA;
        const float* Acur  = (t & 1) ? bufA : bufB;              // A_{t-1}
        const float* Aprev = (t <= 1) ? Acur                     // gamma==0, unused
                                      : ((t & 1) ? bufB : bufA); // A_{t-2}
        if (t == 0) {
            // B_0 = 0 => res = y; fuse into update kernel (first=1)
            fista_quad<<<gF, 256, 0, stream>>>(y, part, H, bufA, bufA, 0.f, 1, bufA);
        } else {
            resid_quad<<<gR, 256, 0, stream>>>(H, Acur, Aprev, gamma, part);
            fista_quad<<<gF, 256, 0, stream>>>(y, part, H, Acur, Aprev, gamma, 0, Anext);
        }
    }
}

// Round 12
// 491.880 us; speedup vs baseline: 5.9263x; 1.3225x over previous
//
#include <hip/hip_runtime.h>
#include <cmath>

// ---- problem dims (fixed per reference) ----
#define YCH 8        // y_channels
#define NTR 16       // trials
#define LLEN 4096    // trial length
#define CK  16       // kernels per channel
#define KS  64       // kernel size
#define ENC 4033     // LLEN - KS + 1
#define NP  128      // YCH*NTR independent problems
#define INV_LIP 0.1f     // 1/10
#define THRESH 0.01f     // LAM/LIP = 0.1/10

#define XW4 272          // float4 slots per 1088-float channel window
#define XP4 289          // padded slots per channel: 272 + 272/16
// f4-slot swizzle: +1 pad slot per 16 -> breaks the 8-way bank conflict of
// the 16B lane stride (banks become {b,b,b+4,b+4,...} = 2-way = free, m136)
#define SW(s) ((s) + ((s) >> 4))

typedef float vfloat4 __attribute__((ext_vector_type(4)));

// volatile 16B LDS load: cannot be rematerialized/split/CSE'd -> exactly one
// ds_read_b128, result register-resident (the r7-r11 remat disease killer)
__device__ __forceinline__ vfloat4 ldvol(const vfloat4* p) {
    return *(const volatile vfloat4*)p;
}

// component of a vfloat4 by compile-time-constant index (folds; no alloca)
#define C4(v, c) ((c) == 0 ? (v).x : (c) == 1 ? (v).y : (c) == 2 ? (v).z : (v).w)
// group-window float f in [0,19] over named regs w0..w4 (folds under unroll)
#define GW(f) ((f) < 4  ? C4(w0, (f))      : \
               (f) < 8  ? C4(w1, (f) - 4)  : \
               (f) < 12 ? C4(w2, (f) - 8)  : \
               (f) < 16 ? C4(w3, (f) - 12) : C4(w4, (f) - 16))

// B over [gi4, gi4+3], zero outside [0, ENC):  B = a + gamma*(a - p)
__device__ __forceinline__ float4 loadB4(const float* __restrict__ A,
                                         const float* __restrict__ P,
                                         float gamma, size_t coff, int gi4)
{
    if (gi4 >= 0 && gi4 + 3 < ENC) {
        float4 a = *(const float4*)(A + coff + gi4);
        float4 p = *(const float4*)(P + coff + gi4);
        return make_float4(fmaf(gamma, a.x - p.x, a.x),
                           fmaf(gamma, a.y - p.y, a.y),
                           fmaf(gamma, a.z - p.z, a.z),
                           fmaf(gamma, a.w - p.w, a.w));
    }
    float r[4];
    #pragma unroll
    for (int j = 0; j < 4; ++j) {
        int gi = gi4 + j;
        if (gi >= 0 && gi < ENC) {
            float a = A[coff + gi], p = P[coff + gi];
            r[j] = fmaf(gamma, a - p, a);
        } else r[j] = 0.f;
    }
    return make_float4(r[0], r[1], r[2], r[3]);
}

// =====================================================================
// resid_quad: part[q][p][t] = sum_{c in quad q, k} B[p,c,t-k]*H[ch,c,k]
// block = (ttile=1024, q, p) -> grid (4,4,128) x 256 thr, 4 outputs/thread.
// Stage quad's 4 B-windows in SWIZZLED LDS, ONE barrier. K split into 4
// k-groups of 16 taps over a rolling named w0..w4 window (r11 identity,
// verified), loaded with volatile b128 reads.
//   identity: out t=t0+4*tid+j needs xs_local[4*tid + 64+j-k], k=16kg+mm;
//   w0 base slot = tid + 12-4kg => group float f = 16-mm+j in [1,19].
// =====================================================================
__global__ __launch_bounds__(256) void resid_quad(
    const float* __restrict__ H,
    const float* __restrict__ Acur, const float* __restrict__ Aprev,
    float gamma, float* __restrict__ part)
{
    __shared__ __align__(16) float xs[4 * XP4 * 4];  // 18496 B (swizzled)
    __shared__ __align__(16) float hs[4 * KS];       //  1024 B
    const int tid = threadIdx.x;
    const int t0  = blockIdx.x * 1024;
    const int c0  = blockIdx.y * 4;
    const int p   = blockIdx.z;
    const int ch  = p >> 4;

    if (tid < 64)
        ((float4*)hs)[tid] = ((const float4*)(H + ((size_t)ch * CK + c0) * KS))[tid];

    const size_t pbase = (size_t)p * CK * ENC;
    // stage 4 channels x 272 f4 = 1088 f4 (4.25 per thread), swizzled slots
    #pragma unroll
    for (int s = 0; s < 5; ++s) {
        int l4 = tid + 256 * s;
        if (l4 < 4 * XW4) {
            int c   = l4 / XW4;
            int off = l4 - c * XW4;
            ((float4*)xs)[c * XP4 + SW(off)] =
                loadB4(Acur, Aprev, gamma,
                       pbase + (size_t)(c0 + c) * ENC, t0 - 64 + 4 * off);
        }
    }
    __syncthreads();

    float acc[4] = {0.f, 0.f, 0.f, 0.f};

    #pragma unroll
    for (int cc = 0; cc < 4; ++cc) {
        const vfloat4* xb = (const vfloat4*)xs + cc * XP4;   // channel base
        const float4*  hc = (const float4*)(hs + cc * KS);

        vfloat4 w0 = ldvol(xb + SW(tid + 12));
        vfloat4 w1 = ldvol(xb + SW(tid + 13));
        vfloat4 w2 = ldvol(xb + SW(tid + 14));
        vfloat4 w3 = ldvol(xb + SW(tid + 15));
        vfloat4 w4 = ldvol(xb + SW(tid + 16));
        #pragma unroll
        for (int kg = 0; kg < 4; ++kg) {
            const float4 h0 = hc[4 * kg], h1 = hc[4 * kg + 1];
            const float4 h2 = hc[4 * kg + 2], h3 = hc[4 * kg + 3];
            #pragma unroll
            for (int mm = 0; mm < 16; ++mm) {       // tap k = 16*kg + mm
                const float4 hv = (mm < 4 ? h0 : mm < 8 ? h1 : mm < 12 ? h2 : h3);
                const float hm = ((mm & 3) == 0 ? hv.x : (mm & 3) == 1 ? hv.y :
                                  (mm & 3) == 2 ? hv.z : hv.w);
                #pragma unroll
                for (int j = 0; j < 4; ++j)
                    acc[j] = fmaf(GW(16 - mm + j), hm, acc[j]);
            }
            if (kg < 3) {   // roll window down 4 slots; old w0 becomes w4
                w4 = w0;
                w0 = ldvol(xb + SW(tid + 8  - 4 * kg));
                w1 = ldvol(xb + SW(tid + 9  - 4 * kg));
                w2 = ldvol(xb + SW(tid + 10 - 4 * kg));
                w3 = ldvol(xb + SW(tid + 11 - 4 * kg));
            }
        }
    }

    const int t = t0 + 4 * tid;
    *(float4*)(part + ((size_t)blockIdx.y * NP + p) * LLEN + t) =
        make_float4(acc[0], acc[1], acc[2], acc[3]);
}

// =====================================================================
// fista_quad: EXACT round-7/11 version (passed; global-traffic bound).
//   staging: rs = y - sum_q part[q]  (reduce fused; first: rs = y)
//   g[c,i] = sum_k rs[i+k]*H[ch,c,k];  x_new = relu(B + g/LIP - thr)
// =====================================================================
__global__ __launch_bounds__(256) void fista_quad(
    const float* __restrict__ y, const float* __restrict__ part,
    const float* __restrict__ H,
    const float* __restrict__ Acur, const float* __restrict__ Aprev,
    float gamma, int first, float* __restrict__ Anext)
{
    __shared__ __align__(16) float rs[XW4 * 4];
    __shared__ __align__(16) float hs[4 * KS];
    const int tid = threadIdx.x;
    const int i0  = blockIdx.x * 1024;
    const int c0  = blockIdx.y * 4;
    const int p   = blockIdx.z;
    const int n = p & 15, ch = p >> 4;

    if (tid < 64)
        ((float4*)hs)[tid] = ((const float4*)(H + ((size_t)ch * CK + c0) * KS))[tid];

    const float* ybase = y + ((size_t)n * YCH + ch) * LLEN;
    #pragma unroll
    for (int s = 0; s < 2; ++s) {
        int l4 = tid + 256 * s;
        if (l4 < XW4) {
            int gi4 = i0 + 4 * l4;
            float4 v;
            if (gi4 + 3 < LLEN) {
                v = *(const float4*)(ybase + gi4);
                if (!first) {
                    #pragma unroll
                    for (int q = 0; q < 4; ++q) {
                        float4 pv = *(const float4*)(part + ((size_t)q * NP + p) * LLEN + gi4);
                        v.x -= pv.x; v.y -= pv.y; v.z -= pv.z; v.w -= pv.w;
                    }
                }
            } else {
                float r[4];
                #pragma unroll
                for (int j = 0; j < 4; ++j) {
                    int gi = gi4 + j;
                    if (gi < LLEN) {
                        float t = ybase[gi];
                        if (!first) {
                            #pragma unroll
                            for (int q = 0; q < 4; ++q)
                                t -= part[((size_t)q * NP + p) * LLEN + gi];
                        }
                        r[j] = t;
                    } else r[j] = 0.f;
                }
                v = make_float4(r[0], r[1], r[2], r[3]);
            }
            ((float4*)rs)[l4] = v;
        }
    }
    __syncthreads();

    // hoisted register window rs[4*tid .. 4*tid+67], shared by 4 channels
    float wf[68];
    const float4* rr = (const float4*)rs + tid;
    #pragma unroll
    for (int q = 0; q < 17; ++q) {
        float4 t4 = rr[q];
        wf[4*q] = t4.x; wf[4*q+1] = t4.y; wf[4*q+2] = t4.z; wf[4*q+3] = t4.w;
    }

    const int i = i0 + 4 * tid;
    const size_t pb = (size_t)p * CK * ENC;
    const bool vec = (i + 3 < ENC);

    float4 a0 = make_float4(0,0,0,0), p0 = make_float4(0,0,0,0);
    if (!first && vec) {
        a0 = *(const float4*)(Acur  + pb + (size_t)c0 * ENC + i);
        p0 = *(const float4*)(Aprev + pb + (size_t)c0 * ENC + i);
    }

    for (int cc = 0; cc < 4; ++cc) {
        float4 a1 = make_float4(0,0,0,0), p1 = make_float4(0,0,0,0);
        if (!first && vec && cc < 3) {
            a1 = *(const float4*)(Acur  + pb + (size_t)(c0 + cc + 1) * ENC + i);
            p1 = *(const float4*)(Aprev + pb + (size_t)(c0 + cc + 1) * ENC + i);
        }

        float acc[4] = {0.f, 0.f, 0.f, 0.f};
        const float4* hc = (const float4*)(hs + cc * KS);
        #pragma unroll
        for (int g = 0; g < 16; ++g) {
            float4 h4 = hc[g];
            float hh[4] = {h4.x, h4.y, h4.z, h4.w};
            #pragma unroll
            for (int m = 0; m < 4; ++m) {
                const int k = 4 * g + m;
                #pragma unroll
                for (int j = 0; j < 4; ++j)
                    acc[j] = fmaf(wf[k + j], hh[m], acc[j]);
            }
        }

        const size_t idx = pb + (size_t)(c0 + cc) * ENC + i;
        if (vec) {
            float B[4] = {0.f, 0.f, 0.f, 0.f};
            if (!first) {
                float av[4] = {a0.x, a0.y, a0.z, a0.w};
                float pv[4] = {p0.x, p0.y, p0.z, p0.w};
                #pragma unroll
                for (int j = 0; j < 4; ++j) B[j] = fmaf(gamma, av[j] - pv[j], av[j]);
            }
            float4 o;
            o.x = fmaxf(fmaf(acc[0], INV_LIP, B[0]) - THRESH, 0.f);
            o.y = fmaxf(fmaf(acc[1], INV_LIP, B[1]) - THRESH, 0.f);
            o.z = fmaxf(fmaf(acc[2], INV_LIP, B[2]) - THRESH, 0.f);
            o.w = fmaxf(fmaf(acc[3], INV_LIP, B[3]) - THRESH, 0.f);
            *(float4*)(Anext + idx) = o;
        } else if (i < ENC) {
            #pragma unroll
            for (int j = 0; j < 4; ++j) {
                if (i + j < ENC) {
                    float B = 0.f;
                    if (!first) {
                        float a = Acur[idx + j], pp = Aprev[idx + j];
                        B = fmaf(gamma, a - pp, a);
                    }
                    Anext[idx + j] = fmaxf(fmaf(acc[j], INV_LIP, B) - THRESH, 0.f);
                }
            }
        }
        a0 = a1; p0 = p1;
    }
}

// =====================================================================
extern "C" void kernel_launch(void* const* d_in, const int* in_sizes, int n_in,
                              void* d_out, int out_size, void* d_ws, size_t ws_size,
                              hipStream_t stream)
{
    const float* y = (const float*)d_in[0];   // [NTR, YCH, LLEN]
    const float* H = (const float*)d_in[1];   // [YCH, CK, 1, KS]
    const size_t XSZ = (size_t)NP * CK * ENC; // 8,259,584 floats

    float* bufA = (float*)d_ws;               // A_t for even t
    float* bufB = (float*)d_out;              // A_t for odd t (A9 -> d_out)
    float* part = bufA + XSZ;                 // [4][NP][LLEN] partial synth sums

    double s[11]; s[0] = 1.0;
    for (int t = 1; t <= 10; ++t) s[t] = 0.5 * (1.0 + sqrt(1.0 + 4.0 * s[t-1] * s[t-1]));

    dim3 gR(4, 4, NP), gF(4, 4, NP);

    for (int t = 0; t < 10; ++t) {
        float gamma = (t == 0) ? 0.f : (float)((s[t-1] - 1.0) / s[t]);
        float* Anext       = (t & 1) ? bufB : bufA;
        const float* Acur  = (t & 1) ? bufA : bufB;              // A_{t-1}
        const float* Aprev = (t <= 1) ? Acur                     // gamma==0, unused
                                      : ((t & 1) ? bufB : bufA); // A_{t-2}
        if (t == 0) {
            // B_0 = 0 => res = y; fuse into update kernel (first=1)
            fista_quad<<<gF, 256, 0, stream>>>(y, part, H, bufA, bufA, 0.f, 1, bufA);
        } else {
            resid_quad<<<gR, 256, 0, stream>>>(H, Acur, Aprev, gamma, part);
            fista_quad<<<gF, 256, 0, stream>>>(y, part, H, Acur, Aprev, gamma, 0, Anext);
        }
    }
}